// Round 5
// baseline (736.916 us; speedup 1.0000x reference)
//
#include <hip/hip_runtime.h>
#include <math.h>

#define BN 4
#define HN 96
#define WN 312
#define CN 384
#define D1 49

// Live domain (verified rounds 0-4, absmax 0.0): ROI rows h in [64,95],
// rm cols x in [62,218]; windows/extents reach [50,230]; cost needed only
// for x in [48,240). There x >= 48 >= d -> all values finite, cnt == 49.
#define HROI0 64
#define HROI 32
#define XOFF 48
#define XLEN 192
#define ESTR 193          // LDS row stride (odd -> column reads conflict-free)
#define TXC 64
#define KCC 16
#define RSTRIDE 116
#define RST2 (KCC*RSTRIDE)   // 1856 floats per R staging buffer

// ---- cost-phase helpers (macros keep all array indexing compile-time) ----
#define LOADR(rq, c0) \
    _Pragma("unroll") for (int ii = 0; ii < 7; ii++) \
        rq[ii] = *(const float4*)(Rbase + (size_t)(sr0 + 16 * ii) * CN + (c0) + scq * 4);

#define WRITER(Rsb, rq) \
    _Pragma("unroll") for (int ii = 0; ii < 7; ii++) { \
        const int row = sr0 + 16 * ii; \
        (Rsb)[(4 * scq + 0) * RSTRIDE + row] = rq[ii].x; \
        (Rsb)[(4 * scq + 1) * RSTRIDE + row] = rq[ii].y; \
        (Rsb)[(4 * scq + 2) * RSTRIDE + row] = rq[ii].z; \
        (Rsb)[(4 * scq + 3) * RSTRIDE + row] = rq[ii].w; }

#define LOADL(Lc, c0) \
    _Pragma("unroll") for (int i = 0; i < 4; i++) { \
        const float4* src = (const float4*)(Lrow + (size_t)(xbase + i) * CN + (c0)); \
        _Pragma("unroll") for (int g = 0; g < 4; g++) { \
            float4 v = src[g]; \
            Lc[i][4 * g + 0] = v.x; Lc[i][4 * g + 1] = v.y; \
            Lc[i][4 * g + 2] = v.z; Lc[i][4 * g + 3] = v.w; } }

#define COMPUTE(Lc, Rsb) \
    _Pragma("unroll") for (int c = 0; c < KCC; c++) { \
        const float4* rp4 = (const float4*)&(Rsb)[c * RSTRIDE + rb]; \
        float4 q0 = rp4[0], q1 = rp4[1], q2 = rp4[2], q3 = rp4[3]; \
        float Rv[16] = {q0.x, q0.y, q0.z, q0.w, q1.x, q1.y, q1.z, q1.w, \
                        q2.x, q2.y, q2.z, q2.w, q3.x, q3.y, q3.z, q3.w}; \
        _Pragma("unroll") for (int j = 0; j < 13; j++) \
            _Pragma("unroll") for (int i = 0; i < 4; i++) \
                acc[j][i] = fmaf(Lc[i][c], Rv[i - j + 12], acc[j][i]); }

// entropy over d for one column x of the E slab (stride ESTR)
__device__ __forceinline__ float ent_col(const float* E, int x)
{
    float v[D1];
#pragma unroll
    for (int d = 0; d < D1; d++) v[d] = E[d * ESTR + x];

    float m = v[0];
#pragma unroll
    for (int d = 1; d < D1; d++) m = fmaxf(m, v[d]);

    float S = 0.f;
    int cnt = 0;
#pragma unroll
    for (int d = 0; d < D1; d++) {
        if (isfinite(v[d])) cnt++;        // always true here; kept for parity
        S += expf((v[d] - m) * 10.0f);
    }
    float lS = logf(S);
    float e_acc = 0.f;
#pragma unroll
    for (int d = 0; d < D1; d++) {
        float l = (v[d] - m) * 10.0f;
        float pe = expf(l) / S;
        if (pe > 1e-8f) e_acc -= pe * (l - lS);
        else            e_acc += 1.8420681e-7f;  // -1e-8*ln(1e-8)
    }
    float out = 0.f;
    if (cnt > 1) out = e_acc / (logf((float)cnt) + 1e-8f);
    return fminf(fmaxf(out, 0.f), 1.f);
}

// run extents in local coords (xl = x-48); exact vs reference cummax form.
__device__ __forceinline__ void extents3(const unsigned long long* vmask, int x,
                                         bool valid, int xglob,
                                         int* pa, int* pb, bool* prm)
{
    int prev = -1;
    int wi = x >> 6;
    unsigned long long m = vmask[wi] & (~0ULL >> (63 - (x & 63)));
    while (true) {
        if (m) { prev = (wi << 6) + 63 - __builtin_clzll(m); break; }
        if (--wi < 0) break;
        m = vmask[wi];
    }
    int nxt = XLEN;
    wi = x >> 6;
    m = vmask[wi] & (~0ULL << (x & 63));
    while (true) {
        if (m) { nxt = (wi << 6) + __builtin_ctzll(m); break; }
        if (++wi >= 3) break;
        m = vmask[wi];
    }
    int a = prev + 1;
    int lo = x - 12; if (lo < 0) lo = 0;
    if (a < lo) a = lo;
    int bb = (nxt > x) ? nxt - 1 : x;
    if (bb > XLEN - 1) bb = XLEN - 1;
    int hi = x + 12; if (hi > XLEN - 1) hi = XLEN - 1;
    if (bb > hi) bb = hi;
    *pa = a; *pb = bb;
    *prm = (!valid) && (xglob >= 62) && (xglob <= 218);
}

// ---------------- fused kernel: cost volume + both refine passes + loss ----------------
// One block per (b, ROI row). 3 waves, wave w computes x-tile [48+64w, 48+64w+64).
// Cost accumulators land directly in the E0 LDS slab; post-processing runs in-block.
__global__ __launch_bounds__(192, 1)
void k_fused(const float* __restrict__ Lf, const float* __restrict__ Rf,
             const float* __restrict__ st, float* __restrict__ accum)
{
    __shared__ float E0[D1 * ESTR];          // 37828 B
    __shared__ float Rpool[3 * 2 * RST2];    // 44544 B; reused as prefix buffer P
    __shared__ unsigned long long vmask[3];
    __shared__ float r1[3], r2[3];

    const int t = threadIdx.x;
    const int w = t >> 6;            // wave id = x-tile id
    const int l = t & 63;
    const int xg = l & 15;
    const int dg = l >> 4;
    const int hp = blockIdx.x;
    const int b = blockIdx.y;
    const int h = HROI0 + hp;
    const int x0 = XOFF + w * TXC;

    const float* Lrow = Lf + (size_t)(b * HN + h) * WN * CN;
    const float* Rbase = Rf + (size_t)(b * HN + h) * WN * CN + (size_t)(x0 - 48) * CN;
    float* Rs0 = Rpool + w * 2 * RST2;
    float* Rs1 = Rs0 + RST2;
    const int rb = 4 * xg - 12 * dg + 36;    // mult of 4 -> aligned b128 reads
    const int d0 = 12 * dg;                  // d-tiles overlap at 12/24/36: duplicate
                                             // threads compute bitwise-identical values
    const int xbase = x0 + 4 * xg;           // in [48,236]: no bounds checks anywhere
    const int sr0 = l >> 2;
    const int scq = l & 3;

    float acc[13][4];
#pragma unroll
    for (int j = 0; j < 13; j++)
#pragma unroll
        for (int i = 0; i < 4; i++) acc[j][i] = 0.f;

    float LcA[4][KCC], LcB[4][KCC];
    float4 rqA[7], rqB[7];

    // prologue: chunk 0 resident, chunk 1 in flight
    LOADL(LcA, 0);
    LOADR(rqA, 0);
    WRITER(Rs0, rqA);
    __syncthreads();
    LOADR(rqB, KCC);
    LOADL(LcB, KCC);

#pragma unroll 1
    for (int k = 0; k < 12; k++) {
        const int c0 = k * 2 * KCC;
        COMPUTE(LcA, Rs0);                   // chunk 2k
        WRITER(Rs1, rqB);
        __syncthreads();
        if (k < 11) { LOADR(rqA, c0 + 2 * KCC); LOADL(LcA, c0 + 2 * KCC); }
        COMPUTE(LcB, Rs1);                   // chunk 2k+1
        if (k < 11) { WRITER(Rs0, rqA); }
        __syncthreads();
        if (k < 11) { LOADR(rqB, c0 + 3 * KCC); LOADL(LcB, c0 + 3 * KCC); }
    }

    // epilogue: accumulators -> E0 slab (duplicate-d writes are bit-identical)
    {
        const int xl = xbase - XOFF;
#pragma unroll
        for (int j = 0; j < 13; j++) {
            float* er = &E0[(d0 + j) * ESTR + xl];
            er[0] = acc[j][0]; er[1] = acc[j][1]; er[2] = acc[j][2]; er[3] = acc[j][3];
        }
    }
    __syncthreads();

    // ---- pass 1: ent0 -> extents ----
    bool valid = (ent_col(E0, t) <= 0.6f);
    unsigned long long bal = __ballot(valid);
    if (l == 0) vmask[w] = bal;
    __syncthreads();
    int a1, b1; bool rm1;
    extents3(vmask, t, valid, XOFF + t, &a1, &b1, &rm1);

    // row prefix sums (pure ascending order, the reference's cumsum form)
    float* P = Rpool;                        // D1*ESTR = 9457 <= 11136 floats
    if (t < D1) {
        const float* er = &E0[t * ESTR];
        float* pr = &P[t * ESTR];
        float s = 0.f;
        pr[0] = 0.f;
#pragma unroll 4
        for (int x = 0; x < XLEN; x++) { s += er[x]; pr[x + 1] = s; }
    }
    __syncthreads();

    // refine1 in-place: window mean for rm1 pixels (all entries finite)
    if (rm1) {
        const float den1 = (float)(b1 - a1 + 1);
#pragma unroll 1
        for (int d = 0; d < D1; d++) {
            float num = P[d * ESTR + b1 + 1] - P[d * ESTR + a1];
            E0[d * ESTR + t] = num / den1;
        }
    }
    __syncthreads();

    // ---- pass 2: ent1 -> extents ----
    bool valid2 = (ent_col(E0, t) <= 0.6f);
    unsigned long long bal2 = __ballot(valid2);
    if (l == 0) vmask[w] = bal2;
    __syncthreads();
    int a2, b2; bool rm2;
    extents3(vmask, t, valid2, XOFF + t, &a2, &b2, &rm2);

    if (t < D1) {
        const float* er = &E0[t * ESTR];
        float* pr = &P[t * ESTR];
        float s = 0.f;
        pr[0] = 0.f;
#pragma unroll 4
        for (int x = 0; x < XLEN; x++) { s += er[x]; pr[x + 1] = s; }
    }
    __syncthreads();

    // ---- refine2 + streaming argmax + smooth-L1 ----
    float sl1 = 0.f, msk = 0.f;
    if (rm2) {
        const float den2 = (float)(b2 - a2 + 1);
        float best = 0.f; int bi = 0;
#pragma unroll 1
        for (int d = 0; d < D1; d++) {
            float val = (P[d * ESTR + b2 + 1] - P[d * ESTR + a2]) / den2;
            if (d == 0 || val > best) { best = val; bi = d; }   // first-max
        }
        float diff = st[(size_t)(b * HN + h) * WN + XOFF + t] * 0.25f - (float)bi;
        float ad = fabsf(diff);
        sl1 = (ad < 1.f) ? 0.5f * ad * ad : ad - 0.5f;
        msk = 1.f;
    }
#pragma unroll
    for (int off = 32; off; off >>= 1) {
        sl1 += __shfl_down(sl1, off);
        msk += __shfl_down(msk, off);
    }
    if (l == 0) { r1[w] = sl1; r2[w] = msk; }
    __syncthreads();
    if (t == 0) {
        atomicAdd(&accum[b * 2], r1[0] + r1[1] + r1[2]);
        atomicAdd(&accum[b * 2 + 1], r2[0] + r2[1] + r2[2]);
    }
}

__global__ void k_finalize(const float* __restrict__ accum, float* __restrict__ out)
{
    if (threadIdx.x == 0 && blockIdx.x == 0) {
        float s = 0.f;
        for (int b = 0; b < BN; b++) {
            float c = accum[2 * b + 1];
            if (c < 1.f) c = 1.f;
            s += accum[2 * b] / c;
        }
        out[0] = s * 0.25f;
    }
}

extern "C" void kernel_launch(void* const* d_in, const int* in_sizes, int n_in,
                              void* d_out, int out_size, void* d_ws, size_t ws_size,
                              hipStream_t stream)
{
    const float* fL = (const float*)d_in[0];
    const float* fR = (const float*)d_in[1];
    const float* st = (const float*)d_in[2];
    float* out = (float*)d_out;
    float* accum = (float*)d_ws;

    hipMemsetAsync(accum, 0, 8 * sizeof(float), stream);
    k_fused<<<dim3(HROI, BN), 192, 0, stream>>>(fL, fR, st, accum);
    k_finalize<<<1, 64, 0, stream>>>(accum, out);
}